// Round 5
// baseline (12.658 us; speedup 1.0000x reference)
//
#include <hip/hip_runtime.h>

// POS extractor, algebraically collapsed + register prefix scans.
//
//   h[b,w,l] = A_w*x0[t] + B_w*x1[t] + C_w*x2[t]   (t = w+l)
//   H[b,n]   = x0[n]*SA[n] + x1[n]*SB[n] + x2[n]*SC[n],
//              SA[n] = sum_{w in [n-47,n] ∩ [0,W)} A_w  (etc.)
//
// Phase AB (fused): wave k loads the channel(s) for cross-product k straight
// from global (L1-deduped across waves), scans in registers (shfl), writes
// only the exclusive prefix to LDS. Phase C: window coeffs from 9 moment
// prefix-differences. Phase D: 3 waves scan the coefficient arrays. Phase E:
// outputs from coefficient prefix-differences. 3 barriers total.

constexpr int L_WIN = 48;                     // int(30*1.6)
constexpr int CHUNK = 512;                    // outputs per block
constexpr int NSAMP = CHUNK + 2 * L_WIN - 2;  // 606 staged samples
constexpr int NWIN  = CHUNK + L_WIN - 1;      // 559 windows per block
constexpr int BLOCK = 576;                    // 9 waves -> one per Q array
constexpr int QLEN  = NSAMP + 1;              // 607 prefix entries
constexpr int QPAD  = 640;
constexpr int PLEN  = NWIN + 1;               // 560 prefix entries
constexpr int PPAD  = 576;

// Inclusive scan of ELEMS register values per lane + 6-step wave scan.
template <int ELEMS>
__device__ __forceinline__ void scan_regs(float (&v)[ELEMS], int lane) {
    float run = 0.0f;
    #pragma unroll
    for (int j = 0; j < ELEMS; ++j) { run += v[j]; v[j] = run; }
    float incl = run;
    #pragma unroll
    for (int d = 1; d < 64; d <<= 1) {
        const float t = __shfl_up(incl, d);
        if (lane >= d) incl += t;
    }
    const float excl = incl - run;
    #pragma unroll
    for (int j = 0; j < ELEMS; ++j) v[j] += excl;
}

__global__ __launch_bounds__(BLOCK)
void pos_kernel(const float* __restrict__ x, float* __restrict__ out,
                int B, int N) {
    const int W  = N - L_WIN;              // 8144 valid windows
    const int b  = blockIdx.y;
    const int n0 = blockIdx.x * CHUNK;
    const int t0 = n0 - (L_WIN - 1);       // first staged sample (may be <0)
    const int w0 = t0;                     // first window index  (may be <0)

    // Q[k] : exclusive prefix of product k over staged samples
    //   k = 0..2 : x0, x1, x2 ; 3..5 : squares ; 6..8 : cross products
    __shared__ float Q[9][QPAD];
    __shared__ float PC[3][PPAD];          // prefix of window coeffs A,B,C

    const float* gx = x + (size_t)b * N * 3;
    const int tid  = threadIdx.x;
    const int wid  = tid >> 6;
    const int lane = tid & 63;

    // ---- phase AB: global -> product regs -> register scan -> LDS prefix ----
    {
        const int k = wid;
        int ca, cb; bool two;
        if (k < 3)      { ca = k;            cb = 0;            two = false; }
        else if (k < 6) { ca = k - 3;        cb = k - 3;        two = true;  }
        else            { ca = (k == 8) ? 1 : 0; cb = (k == 6) ? 1 : 2; two = true; }

        float v[10];
        #pragma unroll
        for (int j = 0; j < 10; ++j) {
            const int s = lane * 10 + j;
            const int t = t0 + s;
            float p = 0.0f;
            if (s < NSAMP && t >= 0 && t < N) {
                const float a = gx[(size_t)3 * t + ca];
                p = two ? a * gx[(size_t)3 * t + cb] : a;
            }
            v[j] = p;
        }
        scan_regs<10>(v, lane);
        if (lane == 0) Q[k][0] = 0.0f;
        #pragma unroll
        for (int j = 0; j < 10; ++j) {
            const int s = lane * 10 + j;
            if (s < NSAMP) Q[k][s + 1] = v[j];   // exclusive prefix at s+1
        }
    }
    __syncthreads();

    // ---- phase C: window coefficients (O(1) per window) ----
    for (int wl = tid; wl < NWIN; wl += BLOCK) {
        const int w = w0 + wl;
        float Ac = 0.0f, Bc = 0.0f, Cc = 0.0f;
        if (w >= 0 && w < W) {
            const float m0  = Q[0][wl + L_WIN] - Q[0][wl];
            const float m1  = Q[1][wl + L_WIN] - Q[1][wl];
            const float m2  = Q[2][wl + L_WIN] - Q[2][wl];
            const float p00 = Q[3][wl + L_WIN] - Q[3][wl];
            const float p11 = Q[4][wl + L_WIN] - Q[4][wl];
            const float p22 = Q[5][wl + L_WIN] - Q[5][wl];
            const float p01 = Q[6][wl + L_WIN] - Q[6][wl];
            const float p02 = Q[7][wl + L_WIN] - Q[7][wl];
            const float p12 = Q[8][wl + L_WIN] - Q[8][wl];
            const float q0 = (float)L_WIN / m0;    // 1/mean per channel
            const float q1 = (float)L_WIN / m1;
            const float q2 = (float)L_WIN / m2;
            // sum S0^2 = sum (Cn1 - Cn2)^2
            float ss0 = p11 * q1 * q1 - 2.f * p12 * q1 * q2 + p22 * q2 * q2;
            // sum S1^2 = sum (-2 Cn0 + Cn1 + Cn2)^2
            float ss1 = 4.f * p00 * q0 * q0 + p11 * q1 * q1 + p22 * q2 * q2
                      - 4.f * p01 * q0 * q1 - 4.f * p02 * q0 * q2
                      + 2.f * p12 * q1 * q2;
            ss0 = fmaxf(ss0, 0.0f);
            const float alpha = sqrtf(ss0 / ss1);  // ddof divisor cancels
            Ac = -2.0f * alpha * q0;
            Bc = (1.0f + alpha) * q1;
            Cc = (alpha - 1.0f) * q2;
        }
        PC[0][wl + 1] = Ac;
        PC[1][wl + 1] = Bc;
        PC[2][wl + 1] = Cc;
    }
    if (tid < 3) PC[tid][0] = 0.0f;
    __syncthreads();

    // ---- phase D: 3 register scans of coefficient arrays (stride 9: no
    //      bank conflicts, gcd(9,32)=1) ----
    if (wid < 3) {
        float v[9];
        #pragma unroll
        for (int j = 0; j < 9; ++j) {
            const int e = lane * 9 + j;
            v[j] = (e < PLEN) ? PC[wid][e] : 0.0f;
        }
        scan_regs<9>(v, lane);
        #pragma unroll
        for (int j = 0; j < 9; ++j) {
            const int e = lane * 9 + j;
            if (e < PLEN) PC[wid][e] = v[j];
        }
    }
    __syncthreads();

    // ---- phase E: outputs (O(1) per output, x re-read is L1-warm) ----
    for (int nl = tid; nl < CHUNK; nl += BLOCK) {
        const int n = n0 + nl;
        const float SA = PC[0][nl + L_WIN] - PC[0][nl];
        const float SB = PC[1][nl + L_WIN] - PC[1][nl];
        const float SC = PC[2][nl + L_WIN] - PC[2][nl];
        const float* p = gx + (size_t)3 * n;
        out[(size_t)b * N + n] = p[0] * SA + p[1] * SB + p[2] * SC;
    }
}

extern "C" void kernel_launch(void* const* d_in, const int* in_sizes, int n_in,
                              void* d_out, int out_size, void* d_ws, size_t ws_size,
                              hipStream_t stream) {
    const float* x = (const float*)d_in[0];
    float* out = (float*)d_out;
    const int B = 32;
    const int N = in_sizes[0] / (B * 3);   // 8192
    dim3 grid(N / CHUNK, B);               // 16 x 32 = 512 blocks
    pos_kernel<<<grid, BLOCK, 0, stream>>>(x, out, B, N);
}

// Round 6
// 10.022 us; speedup vs baseline: 1.2630x; 1.2630x over previous
//
#include <hip/hip_runtime.h>

// POS extractor, algebraically collapsed + prefix-sum sliding windows.
// Round-5: R3 structure (coalesced product staging -> 9 wave scans ->
// coeffs -> 3 scans -> outputs) but 4 blocks/CU (CHUNK=256, BLOCK=256,
// 1024 blocks) to overlap the barrier chain across blocks, plus fast
// rcp/rsq/sqrt intrinsics in the coefficient math.
//
//   h[b,w,l] = A_w*x0[t] + B_w*x1[t] + C_w*x2[t]   (t = w+l)
//   H[b,n]   = x0[n]*SA[n] + x1[n]*SB[n] + x2[n]*SC[n],
//              SA[n] = sum_{w in [n-47,n] ∩ [0,W)} A_w  (etc.)

constexpr int L_WIN = 48;                     // int(30*1.6)
constexpr int CHUNK = 256;                    // outputs per block
constexpr int NSAMP = CHUNK + 2 * L_WIN - 2;  // 350 staged samples
constexpr int NWIN  = CHUNK + L_WIN - 1;      // 303 windows per block
constexpr int BLOCK = 256;                    // 4 waves
constexpr int NWAVE = BLOCK / 64;
constexpr int QLEN  = NSAMP + 1;              // 351 prefix entries
constexpr int QPAD  = 392;                    // >= 64*6; %32==8 staggers banks
constexpr int PLEN  = NWIN + 1;               // 304 prefix entries
constexpr int PPAD  = 328;                    // >= 64*5; %32==8

// Inclusive scan of ELEMS register values per lane + 6-step wave scan.
template <int ELEMS>
__device__ __forceinline__ void scan_regs(float (&v)[ELEMS], int lane) {
    float run = 0.0f;
    #pragma unroll
    for (int j = 0; j < ELEMS; ++j) { run += v[j]; v[j] = run; }
    float incl = run;
    #pragma unroll
    for (int d = 1; d < 64; d <<= 1) {
        const float t = __shfl_up(incl, d);
        if (lane >= d) incl += t;
    }
    const float excl = incl - run;
    #pragma unroll
    for (int j = 0; j < ELEMS; ++j) v[j] += excl;
}

// In-place wave scan of a[0..len), ELEMS consecutive elements per lane.
template <int ELEMS>
__device__ __forceinline__ void wave_scan_lds(float* a, int len, int lane) {
    float v[ELEMS];
    #pragma unroll
    for (int j = 0; j < ELEMS; ++j) {
        const int e = lane * ELEMS + j;
        v[j] = (e < len) ? a[e] : 0.0f;
    }
    scan_regs<ELEMS>(v, lane);
    #pragma unroll
    for (int j = 0; j < ELEMS; ++j) {
        const int e = lane * ELEMS + j;
        if (e < len) a[e] = v[j];
    }
}

__global__ __launch_bounds__(BLOCK)
void pos_kernel(const float* __restrict__ x, float* __restrict__ out,
                int B, int N) {
    const int W  = N - L_WIN;              // 8144 valid windows
    const int b  = blockIdx.y;
    const int n0 = blockIdx.x * CHUNK;
    const int t0 = n0 - (L_WIN - 1);       // first staged sample (may be <0)
    const int w0 = t0;                     // first window index  (may be <0)

    // Q[k] : exclusive prefix of product k over staged samples
    //   k = 0..2 : x0, x1, x2 ; 3..5 : squares ; 6..8 : cross products
    __shared__ float Q[9][QPAD];
    __shared__ float PC[3][PPAD];          // prefix of window coeffs A,B,C

    const float* gx = x + (size_t)b * N * 3;
    const int tid  = threadIdx.x;
    const int wid  = tid >> 6;
    const int lane = tid & 63;

    // ---- phase A: coalesced loads -> 9 per-sample products -> LDS ----
    for (int i = tid; i < NSAMP; i += BLOCK) {
        const int t = t0 + i;
        float x0 = 0.0f, x1 = 0.0f, x2 = 0.0f;
        if (t >= 0 && t < N) {             // OOB samples only feed invalid
            const float* p = gx + (size_t)3 * t;   // windows (coeffs forced 0)
            x0 = p[0]; x1 = p[1]; x2 = p[2];
        }
        Q[0][i + 1] = x0;       Q[1][i + 1] = x1;       Q[2][i + 1] = x2;
        Q[3][i + 1] = x0 * x0;  Q[4][i + 1] = x1 * x1;  Q[5][i + 1] = x2 * x2;
        Q[6][i + 1] = x0 * x1;  Q[7][i + 1] = x0 * x2;  Q[8][i + 1] = x1 * x2;
    }
    if (tid < 9) Q[tid][0] = 0.0f;
    __syncthreads();

    // ---- phase B: 9 prefix scans over 4 waves ----
    for (int k = wid; k < 9; k += NWAVE)
        wave_scan_lds<6>(&Q[k][0], QLEN, lane);
    __syncthreads();

    // ---- phase C: window coefficients (O(1) per window, fast math) ----
    for (int wl = tid; wl < NWIN; wl += BLOCK) {
        const int w = w0 + wl;
        float Ac = 0.0f, Bc = 0.0f, Cc = 0.0f;
        if (w >= 0 && w < W) {
            const float m0  = Q[0][wl + L_WIN] - Q[0][wl];
            const float m1  = Q[1][wl + L_WIN] - Q[1][wl];
            const float m2  = Q[2][wl + L_WIN] - Q[2][wl];
            const float p00 = Q[3][wl + L_WIN] - Q[3][wl];
            const float p11 = Q[4][wl + L_WIN] - Q[4][wl];
            const float p22 = Q[5][wl + L_WIN] - Q[5][wl];
            const float p01 = Q[6][wl + L_WIN] - Q[6][wl];
            const float p02 = Q[7][wl + L_WIN] - Q[7][wl];
            const float p12 = Q[8][wl + L_WIN] - Q[8][wl];
            // 1/mean per channel (m_i ~ 48, well-conditioned for v_rcp)
            const float q0 = (float)L_WIN * __builtin_amdgcn_rcpf(m0);
            const float q1 = (float)L_WIN * __builtin_amdgcn_rcpf(m1);
            const float q2 = (float)L_WIN * __builtin_amdgcn_rcpf(m2);
            // sum S0^2 = sum (Cn1 - Cn2)^2
            float ss0 = p11 * q1 * q1 - 2.f * p12 * q1 * q2 + p22 * q2 * q2;
            // sum S1^2 = sum (-2 Cn0 + Cn1 + Cn2)^2
            float ss1 = 4.f * p00 * q0 * q0 + p11 * q1 * q1 + p22 * q2 * q2
                      - 4.f * p01 * q0 * q1 - 4.f * p02 * q0 * q2
                      + 2.f * p12 * q1 * q2;
            ss0 = fmaxf(ss0, 0.0f);
            // alpha = sqrt(ss0/ss1); ddof divisor cancels
            const float alpha = __builtin_amdgcn_sqrtf(ss0) *
                                __builtin_amdgcn_rsqf(ss1);
            Ac = -2.0f * alpha * q0;
            Bc = (1.0f + alpha) * q1;
            Cc = (alpha - 1.0f) * q2;
        }
        PC[0][wl + 1] = Ac;
        PC[1][wl + 1] = Bc;
        PC[2][wl + 1] = Cc;
    }
    if (tid < 3) PC[tid][0] = 0.0f;
    __syncthreads();

    // ---- phase D: 3 prefix scans of coefficient arrays ----
    if (wid < 3) wave_scan_lds<5>(&PC[wid][0], PLEN, lane);
    __syncthreads();

    // ---- phase E: outputs (one round: nl = tid; coalesced, conflict-free) --
    {
        const int nl = tid;
        const int n = n0 + nl;
        const float SA = PC[0][nl + L_WIN] - PC[0][nl];
        const float SB = PC[1][nl + L_WIN] - PC[1][nl];
        const float SC = PC[2][nl + L_WIN] - PC[2][nl];
        const float* p = gx + (size_t)3 * n;       // L1/L2-warm from phase A
        out[(size_t)b * N + n] = p[0] * SA + p[1] * SB + p[2] * SC;
    }
}

extern "C" void kernel_launch(void* const* d_in, const int* in_sizes, int n_in,
                              void* d_out, int out_size, void* d_ws, size_t ws_size,
                              hipStream_t stream) {
    const float* x = (const float*)d_in[0];
    float* out = (float*)d_out;
    const int B = 32;
    const int N = in_sizes[0] / (B * 3);   // 8192
    dim3 grid(N / CHUNK, B);               // 32 x 32 = 1024 blocks, 4/CU
    pos_kernel<<<grid, BLOCK, 0, stream>>>(x, out, B, N);
}